// Round 2
// baseline (1291.380 us; speedup 1.0000x reference)
//
#include <hip/hip_runtime.h>
#include <hip/hip_bf16.h>
#include <stdint.h>

typedef unsigned short u16;
typedef __bf16 bf16_t;
typedef bf16_t bf16x8 __attribute__((ext_vector_type(8)));
typedef u16    u16x8  __attribute__((ext_vector_type(8)));
typedef float  f32x4  __attribute__((ext_vector_type(4)));

#define BSZ    256
#define NATOMS 128
#define INF    128
#define HH     256
#define H3     768
#define MAXV   6
#define OUTF   256
#define KFC    (HH * MAXV)   // 1536

__device__ __forceinline__ u16 f2bf(float f) {
  union { float f; unsigned u; } v; v.f = f;
  unsigned u = v.u;
  unsigned r = (u + 0x7FFFu + ((u >> 16) & 1u)) >> 16;  // RNE
  return (u16)r;
}
__device__ __forceinline__ float bf2f(u16 h) {
  union { unsigned u; float f; } v; v.u = ((unsigned)h) << 16;
  return v.f;
}
__device__ __forceinline__ f32x4 mfma_bf16(u16x8 a, u16x8 b, f32x4 c) {
  return __builtin_amdgcn_mfma_f32_16x16x32_bf16(
      __builtin_bit_cast(bf16x8, a), __builtin_bit_cast(bf16x8, b), c, 0, 0, 0);
}

// ---------------- prep: W_hh and W_fc fp32 -> bf16 ----------------
__global__ void k_prep(const float* __restrict__ whh, u16* __restrict__ whho,
                       const float* __restrict__ wfc, u16* __restrict__ wfco) {
  int i = blockIdx.x * 256 + threadIdx.x;
  if (i < H3 * HH) whho[i] = f2bf(whh[i]);
  if (i < OUTF * KFC) wfco[i] = f2bf(wfc[i]);
}

// ---------------- stage 1: x_proj = x @ W_ih^T + b_ih (bf16 out) ----------------
// M=32768, N=768, K=128. BM=BN=64, BK=32, 256 thr (4 waves, 2x2 of 32x32).
__global__ __launch_bounds__(256) void k_xproj(const float* __restrict__ X,
                                               const float* __restrict__ W,
                                               const float* __restrict__ bias,
                                               u16* __restrict__ out) {
  __shared__ __align__(16) u16 As[64][40];
  __shared__ __align__(16) u16 Bs[64][40];
  const int m0 = blockIdx.x * 64, n0 = blockIdx.y * 64;
  const int tid = threadIdx.x, lane = tid & 63, wid = tid >> 6;
  const int wm = (wid & 1) * 32, wn = (wid >> 1) * 32;
  const int lrow = tid >> 2, lcol = (tid & 3) * 8;
  const f32x4 zero = {0.f, 0.f, 0.f, 0.f};
  f32x4 acc[2][2];
#pragma unroll
  for (int mi = 0; mi < 2; mi++)
#pragma unroll
    for (int ni = 0; ni < 2; ni++) acc[mi][ni] = zero;

  for (int kk = 0; kk < INF; kk += 32) {
    const float* ap = X + (size_t)(m0 + lrow) * INF + kk + lcol;
    const float* bp = W + (size_t)(n0 + lrow) * INF + kk + lcol;
    u16x8 av, bv;
#pragma unroll
    for (int j = 0; j < 8; j++) { av[j] = f2bf(ap[j]); bv[j] = f2bf(bp[j]); }
    *(u16x8*)&As[lrow][lcol] = av;
    *(u16x8*)&Bs[lrow][lcol] = bv;
    __syncthreads();
    u16x8 afr[2], bfr[2];
#pragma unroll
    for (int mi = 0; mi < 2; mi++)
      afr[mi] = *(const u16x8*)&As[wm + mi * 16 + (lane & 15)][(lane >> 4) * 8];
#pragma unroll
    for (int ni = 0; ni < 2; ni++)
      bfr[ni] = *(const u16x8*)&Bs[wn + ni * 16 + (lane & 15)][(lane >> 4) * 8];
#pragma unroll
    for (int mi = 0; mi < 2; mi++)
#pragma unroll
      for (int ni = 0; ni < 2; ni++) acc[mi][ni] = mfma_bf16(afr[mi], bfr[ni], acc[mi][ni]);
    __syncthreads();
  }
#pragma unroll
  for (int mi = 0; mi < 2; mi++)
#pragma unroll
    for (int ni = 0; ni < 2; ni++) {
      int n = n0 + wn + ni * 16 + (lane & 15);
      float bv = bias[n];
#pragma unroll
      for (int r = 0; r < 4; r++) {
        int m = m0 + wm + mi * 16 + (lane >> 4) * 4 + r;
        out[(size_t)m * H3 + n] = f2bf(acc[mi][ni][r] + bv);
      }
    }
}

// ---------------- stage 2: GRU recurrence, W_hh register-resident ----------------
// 16 blocks x 512 thr (8 waves); block owns 16 batch rows for all 128 steps.
// Each wave holds a 96x256 W_hh slice as 48 B-fragments = 192 VGPRs (fits the
// 256-VGPR arch budget at 2 waves/EU; R1's 4-wave variant needed 384 -> spilled).
__global__ __launch_bounds__(512, 2) void k_gru(const u16* __restrict__ Whh,
                                                const float* __restrict__ bhh,
                                                const u16* __restrict__ xp,
                                                u16* __restrict__ rnn) {
  __shared__ __align__(16) u16 hA[16 * 264];   // bf16 h, A-operand layout (+8 pad)
  __shared__ float hF[16 * 256];               // fp32 h state
  __shared__ float gh[16 * 776];               // h @ Whh^T (+8 pad)
  __shared__ float bhh_s[H3];
  const int tid = threadIdx.x, lane = tid & 63, wid = tid >> 6;  // wid in [0,8)
  const int b0 = blockIdx.x * 16;

  for (int i = tid; i < 16 * 264; i += 512) hA[i] = 0;
  for (int i = tid; i < 16 * 256; i += 512) hF[i] = 0.f;
  for (int i = tid; i < H3; i += 512) bhh_s[i] = bhh[i];

  const int nbase = wid * 96;  // this wave's 96 gate rows
  u16x8 wf[6][8];              // 48 frags * 4 VGPR = 192 VGPRs
#pragma unroll
  for (int nt = 0; nt < 6; nt++)
#pragma unroll
    for (int kt = 0; kt < 8; kt++) {
      int n = nbase + nt * 16 + (lane & 15);
      int k = kt * 32 + (lane >> 4) * 8;
      wf[nt][kt] = *(const u16x8*)(Whh + (size_t)n * HH + k);
    }
  __syncthreads();

  for (int t = 0; t < NATOMS; t++) {
    // ---- gh = h @ Whh^T (MFMA, M=16 all valid batch rows) ----
    u16x8 af[8];
#pragma unroll
    for (int kt = 0; kt < 8; kt++)
      af[kt] = *(const u16x8*)&hA[(lane & 15) * 264 + kt * 32 + (lane >> 4) * 8];
    const f32x4 zero = {0.f, 0.f, 0.f, 0.f};
#pragma unroll
    for (int np = 0; np < 3; np++) {  // pairs of 16-wide n-tiles for ILP
      f32x4 a0 = zero, a1 = zero;
#pragma unroll
      for (int kt = 0; kt < 8; kt++) {
        a0 = mfma_bf16(af[kt], wf[np * 2][kt], a0);
        a1 = mfma_bf16(af[kt], wf[np * 2 + 1][kt], a1);
      }
      int ncol = nbase + np * 32 + (lane & 15);
      int mrow = (lane >> 4) * 4;
#pragma unroll
      for (int r = 0; r < 4; r++) {
        gh[(mrow + r) * 776 + ncol] = a0[r];
        gh[(mrow + r) * 776 + ncol + 16] = a1[r];
      }
    }
    __syncthreads();
    // ---- gates + state update (fp32), 16x256 h-updates over 512 threads ----
#pragma unroll
    for (int rep = 0; rep < 8; rep++) {
      int linear = rep * 512 + tid;
      int m = linear >> 8, i = linear & 255;
      size_t xbase = ((size_t)(b0 + m) * NATOMS + t) * H3;
      float xr = bf2f(xp[xbase + i]);
      float xz = bf2f(xp[xbase + 256 + i]);
      float xn = bf2f(xp[xbase + 512 + i]);
      float hr = gh[m * 776 + i] + bhh_s[i];
      float hz = gh[m * 776 + 256 + i] + bhh_s[256 + i];
      float hn = gh[m * 776 + 512 + i] + bhh_s[512 + i];
      float r = 1.f / (1.f + __expf(-(xr + hr)));
      float z = 1.f / (1.f + __expf(-(xz + hz)));
      float e = __expf(2.f * (xn + r * hn));   // tanh(x) = 1 - 2/(e^{2x}+1)
      float nn = 1.f - 2.f / (e + 1.f);
      float h = hF[m * 256 + i];
      float hnew = (1.f - z) * nn + z * h;
      hF[m * 256 + i] = hnew;
      u16 hb = f2bf(hnew);
      hA[m * 264 + i] = hb;
      rnn[((size_t)(b0 + m) * NATOMS + t) * HH + i] = hb;
    }
    __syncthreads();
  }
}

// ---------------- stage 3: out = leaky(gather(rnn) @ W_fc^T + b_fc) ----------------
// M=32768, N=256, K=1536; gather fused into A-tile load; W_fc pre-converted bf16.
__global__ __launch_bounds__(256) void k_fc(const u16* __restrict__ rnn,
                                            const int* __restrict__ bonded,
                                            const u16* __restrict__ W,
                                            const float* __restrict__ bias,
                                            float* __restrict__ out) {
  __shared__ __align__(16) u16 As[64][40];
  __shared__ __align__(16) u16 Bs[64][40];
  const int m0 = blockIdx.x * 64, n0 = blockIdx.y * 64;
  const int tid = threadIdx.x, lane = tid & 63, wid = tid >> 6;
  const int wm = (wid & 1) * 32, wn = (wid >> 1) * 32;
  const int lrow = tid >> 2, lcol = (tid & 3) * 8;
  const int m = m0 + lrow;
  const int b = m >> 7, atom = m & 127;
  const int* bptr = bonded + (size_t)(b * NATOMS + atom) * MAXV;
  const f32x4 zero = {0.f, 0.f, 0.f, 0.f};
  f32x4 acc[2][2];
#pragma unroll
  for (int mi = 0; mi < 2; mi++)
#pragma unroll
    for (int ni = 0; ni < 2; ni++) acc[mi][ni] = zero;

  for (int kk = 0; kk < KFC; kk += 32) {
    int k = kk + lcol;
    int v = k >> 8, kr = k & 255;
    int idx = bptr[v];
    u16x8 av = *(const u16x8*)(rnn + (size_t)(b * NATOMS + idx) * HH + kr);
    u16x8 bv = *(const u16x8*)(W + (size_t)(n0 + lrow) * KFC + k);
    *(u16x8*)&As[lrow][lcol] = av;
    *(u16x8*)&Bs[lrow][lcol] = bv;
    __syncthreads();
    u16x8 afr[2], bfr[2];
#pragma unroll
    for (int mi = 0; mi < 2; mi++)
      afr[mi] = *(const u16x8*)&As[wm + mi * 16 + (lane & 15)][(lane >> 4) * 8];
#pragma unroll
    for (int ni = 0; ni < 2; ni++)
      bfr[ni] = *(const u16x8*)&Bs[wn + ni * 16 + (lane & 15)][(lane >> 4) * 8];
#pragma unroll
    for (int mi = 0; mi < 2; mi++)
#pragma unroll
      for (int ni = 0; ni < 2; ni++) acc[mi][ni] = mfma_bf16(afr[mi], bfr[ni], acc[mi][ni]);
    __syncthreads();
  }
#pragma unroll
  for (int mi = 0; mi < 2; mi++)
#pragma unroll
    for (int ni = 0; ni < 2; ni++) {
      int n = n0 + wn + ni * 16 + (lane & 15);
      float bv = bias[n];
#pragma unroll
      for (int r = 0; r < 4; r++) {
        int mm = m0 + wm + mi * 16 + (lane >> 4) * 4 + r;
        float vv = acc[mi][ni][r] + bv;
        out[(size_t)mm * OUTF + n] = vv >= 0.f ? vv : 0.1f * vv;
      }
    }
}

extern "C" void kernel_launch(void* const* d_in, const int* in_sizes, int n_in,
                              void* d_out, int out_size, void* d_ws, size_t ws_size,
                              hipStream_t stream) {
  const float* x      = (const float*)d_in[0];
  const int*   bonded = (const int*)d_in[1];
  const float* Wih    = (const float*)d_in[2];
  const float* Whh    = (const float*)d_in[3];
  const float* bih    = (const float*)d_in[4];
  const float* bhh    = (const float*)d_in[5];
  const float* Wfc    = (const float*)d_in[6];
  const float* bfc    = (const float*)d_in[7];
  float* out = (float*)d_out;

  char* ws = (char*)d_ws;
  u16* xp   = (u16*)(ws);                                    // 50,331,648 B
  u16* rnn  = (u16*)(ws + 50331648);                         // 16,777,216 B
  u16* whhb = (u16*)(ws + 50331648 + 16777216);              //    393,216 B
  u16* wfcb = (u16*)(ws + 50331648 + 16777216 + 393216);     //    786,432 B

  k_prep<<<(OUTF * KFC + 255) / 256, 256, 0, stream>>>(Whh, whhb, Wfc, wfcb);
  k_xproj<<<dim3(512, 12), 256, 0, stream>>>(x, Wih, bih, xp);
  k_gru<<<16, 512, 0, stream>>>(whhb, bhh, xp, rnn);
  k_fc<<<dim3(512, 4), 256, 0, stream>>>(rnn, bonded, wfcb, bfc, out);
}

// Round 3
// 453.130 us; speedup vs baseline: 2.8499x; 2.8499x over previous
//
#include <hip/hip_runtime.h>
#include <hip/hip_bf16.h>
#include <stdint.h>

typedef unsigned short u16;
typedef __bf16 bf16_t;
typedef bf16_t bf16x8 __attribute__((ext_vector_type(8)));
typedef u16    u16x8  __attribute__((ext_vector_type(8)));
typedef float  f32x4  __attribute__((ext_vector_type(4)));

#define BSZ    256
#define NATOMS 128
#define INF    128
#define HH     256
#define H3     768
#define MAXV   6
#define OUTF   256
#define KFC    (HH * MAXV)   // 1536
#define GHP    778           // gh row pitch (floats): 4*778 % 32 == 8 -> 2-way only

__device__ __forceinline__ u16 f2bf(float f) {
  union { float f; unsigned u; } v; v.f = f;
  unsigned u = v.u;
  unsigned r = (u + 0x7FFFu + ((u >> 16) & 1u)) >> 16;  // RNE
  return (u16)r;
}
__device__ __forceinline__ float bf2f(u16 h) {
  union { unsigned u; float f; } v; v.u = ((unsigned)h) << 16;
  return v.f;
}
__device__ __forceinline__ f32x4 mfma_bf16(u16x8 a, u16x8 b, f32x4 c) {
  return __builtin_amdgcn_mfma_f32_16x16x32_bf16(
      __builtin_bit_cast(bf16x8, a), __builtin_bit_cast(bf16x8, b), c, 0, 0, 0);
}

// ---------------- prep: W_hh and W_fc fp32 -> bf16 ----------------
__global__ void k_prep(const float* __restrict__ whh, u16* __restrict__ whho,
                       const float* __restrict__ wfc, u16* __restrict__ wfco) {
  int i = blockIdx.x * 256 + threadIdx.x;
  if (i < H3 * HH) whho[i] = f2bf(whh[i]);
  if (i < OUTF * KFC) wfco[i] = f2bf(wfc[i]);
}

// ---------------- stage 1: x_proj = x @ W_ih^T + b_ih (bf16 out) ----------------
__global__ __launch_bounds__(256) void k_xproj(const float* __restrict__ X,
                                               const float* __restrict__ W,
                                               const float* __restrict__ bias,
                                               u16* __restrict__ out) {
  __shared__ __align__(16) u16 As[64][40];
  __shared__ __align__(16) u16 Bs[64][40];
  const int m0 = blockIdx.x * 64, n0 = blockIdx.y * 64;
  const int tid = threadIdx.x, lane = tid & 63, wid = tid >> 6;
  const int wm = (wid & 1) * 32, wn = (wid >> 1) * 32;
  const int lrow = tid >> 2, lcol = (tid & 3) * 8;
  const f32x4 zero = {0.f, 0.f, 0.f, 0.f};
  f32x4 acc[2][2];
#pragma unroll
  for (int mi = 0; mi < 2; mi++)
#pragma unroll
    for (int ni = 0; ni < 2; ni++) acc[mi][ni] = zero;

  for (int kk = 0; kk < INF; kk += 32) {
    const float* ap = X + (size_t)(m0 + lrow) * INF + kk + lcol;
    const float* bp = W + (size_t)(n0 + lrow) * INF + kk + lcol;
    u16x8 av, bv;
#pragma unroll
    for (int j = 0; j < 8; j++) { av[j] = f2bf(ap[j]); bv[j] = f2bf(bp[j]); }
    *(u16x8*)&As[lrow][lcol] = av;
    *(u16x8*)&Bs[lrow][lcol] = bv;
    __syncthreads();
    u16x8 afr[2], bfr[2];
#pragma unroll
    for (int mi = 0; mi < 2; mi++)
      afr[mi] = *(const u16x8*)&As[wm + mi * 16 + (lane & 15)][(lane >> 4) * 8];
#pragma unroll
    for (int ni = 0; ni < 2; ni++)
      bfr[ni] = *(const u16x8*)&Bs[wn + ni * 16 + (lane & 15)][(lane >> 4) * 8];
#pragma unroll
    for (int mi = 0; mi < 2; mi++)
#pragma unroll
      for (int ni = 0; ni < 2; ni++) acc[mi][ni] = mfma_bf16(afr[mi], bfr[ni], acc[mi][ni]);
    __syncthreads();
  }
#pragma unroll
  for (int mi = 0; mi < 2; mi++)
#pragma unroll
    for (int ni = 0; ni < 2; ni++) {
      int n = n0 + wn + ni * 16 + (lane & 15);
      float bv = bias[n];
#pragma unroll
      for (int r = 0; r < 4; r++) {
        int m = m0 + wm + mi * 16 + (lane >> 4) * 4 + r;
        out[(size_t)m * H3 + n] = f2bf(acc[mi][ni][r] + bv);
      }
    }
}

// ---------------- stage 2: GRU recurrence, W_hh register-resident ----------------
// 32 blocks x 512 thr (8 waves); block owns 8 batch rows for all 128 steps.
// Each wave holds a 96x256 W_hh slice as 48 B-fragments = 192 VGPRs.
// amdgpu_waves_per_eu(2,2): pin occupancy target so the allocator uses the full
// 256-reg/wave budget instead of spilling to hit 4 waves/EU (R2: VGPR=128 + spills).
__global__ void __attribute__((amdgpu_flat_work_group_size(512, 512),
                               amdgpu_waves_per_eu(2, 2)))
k_gru(const u16* __restrict__ Whh, const float* __restrict__ bhh,
      const u16* __restrict__ xp, u16* __restrict__ rnn) {
  __shared__ __align__(16) u16 hA[16 * 264];   // bf16 h, A-operand layout (+8 pad)
  __shared__ float gh[16 * GHP];               // h @ Whh^T
  __shared__ float bhh_s[H3];
  const int tid = threadIdx.x, lane = tid & 63, wid = tid >> 6;  // wid in [0,8)
  const int b0 = blockIdx.x * 8;

  for (int i = tid; i < 16 * 264; i += 512) hA[i] = 0;
  for (int i = tid; i < H3; i += 512) bhh_s[i] = bhh[i];

  const int nbase = wid * 96;  // this wave's 96 gate rows
  u16x8 wf[6][8];              // 48 frags * 4 VGPR = 192 VGPRs
#pragma unroll
  for (int nt = 0; nt < 6; nt++)
#pragma unroll
    for (int kt = 0; kt < 8; kt++) {
      int n = nbase + nt * 16 + (lane & 15);
      int k = kt * 32 + (lane >> 4) * 8;
      wf[nt][kt] = *(const u16x8*)(Whh + (size_t)n * HH + k);
    }
  // Pin fragments into VGPRs: opaque asm def prevents rematerializing the
  // global loads inside the t-loop.
#pragma unroll
  for (int nt = 0; nt < 6; nt++)
#pragma unroll
    for (int kt = 0; kt < 8; kt++) asm volatile("" : "+v"(wf[nt][kt]));
  __syncthreads();

  // per-thread fp32 h state: thread owns (m = 2*rep + (tid>>8), i = tid&255)
  float hreg[4] = {0.f, 0.f, 0.f, 0.f};
  const int my_i = tid & 255, m_off = tid >> 8;

  for (int t = 0; t < NATOMS; t++) {
    // ---- gh = h @ Whh^T (MFMA) ----
    u16x8 af[8];
#pragma unroll
    for (int kt = 0; kt < 8; kt++)
      af[kt] = *(const u16x8*)&hA[(lane & 15) * 264 + kt * 32 + (lane >> 4) * 8];
    const f32x4 zero = {0.f, 0.f, 0.f, 0.f};
#pragma unroll
    for (int np = 0; np < 3; np++) {
      f32x4 a0 = zero, a1 = zero;
#pragma unroll
      for (int kt = 0; kt < 8; kt++) {
        a0 = mfma_bf16(af[kt], wf[np * 2][kt], a0);
        a1 = mfma_bf16(af[kt], wf[np * 2 + 1][kt], a1);
      }
      int ncol = nbase + np * 32 + (lane & 15);
      int mrow = (lane >> 4) * 4;
#pragma unroll
      for (int r = 0; r < 4; r++) {
        gh[(mrow + r) * GHP + ncol] = a0[r];
        gh[(mrow + r) * GHP + ncol + 16] = a1[r];
      }
    }
    __syncthreads();
    // ---- gates + state update (fp32); 8x256 elems over 512 threads ----
#pragma unroll
    for (int rep = 0; rep < 4; rep++) {
      int m = rep * 2 + m_off, i = my_i;
      size_t xbase = ((size_t)(b0 + m) * NATOMS + t) * H3;
      float xr = bf2f(xp[xbase + i]);
      float xz = bf2f(xp[xbase + 256 + i]);
      float xn = bf2f(xp[xbase + 512 + i]);
      float hr = gh[m * GHP + i] + bhh_s[i];
      float hz = gh[m * GHP + 256 + i] + bhh_s[256 + i];
      float hn = gh[m * GHP + 512 + i] + bhh_s[512 + i];
      float r = 1.f / (1.f + __expf(-(xr + hr)));
      float z = 1.f / (1.f + __expf(-(xz + hz)));
      float e = __expf(2.f * (xn + r * hn));   // tanh(x) = 1 - 2/(e^{2x}+1)
      float nn = 1.f - 2.f / (e + 1.f);
      float hnew = (1.f - z) * nn + z * hreg[rep];
      hreg[rep] = hnew;
      u16 hb = f2bf(hnew);
      hA[m * 264 + i] = hb;
      rnn[((size_t)(b0 + m) * NATOMS + t) * HH + i] = hb;
    }
    __syncthreads();
  }
}

// ---------------- stage 3: out = leaky(gather(rnn) @ W_fc^T + b_fc) ----------------
__global__ __launch_bounds__(256) void k_fc(const u16* __restrict__ rnn,
                                            const int* __restrict__ bonded,
                                            const u16* __restrict__ W,
                                            const float* __restrict__ bias,
                                            float* __restrict__ out) {
  __shared__ __align__(16) u16 As[64][40];
  __shared__ __align__(16) u16 Bs[64][40];
  const int m0 = blockIdx.x * 64, n0 = blockIdx.y * 64;
  const int tid = threadIdx.x, lane = tid & 63, wid = tid >> 6;
  const int wm = (wid & 1) * 32, wn = (wid >> 1) * 32;
  const int lrow = tid >> 2, lcol = (tid & 3) * 8;
  const int m = m0 + lrow;
  const int b = m >> 7, atom = m & 127;
  const int* bptr = bonded + (size_t)(b * NATOMS + atom) * MAXV;
  const f32x4 zero = {0.f, 0.f, 0.f, 0.f};
  f32x4 acc[2][2];
#pragma unroll
  for (int mi = 0; mi < 2; mi++)
#pragma unroll
    for (int ni = 0; ni < 2; ni++) acc[mi][ni] = zero;

  for (int kk = 0; kk < KFC; kk += 32) {
    int k = kk + lcol;
    int v = k >> 8, kr = k & 255;
    int idx = bptr[v];
    u16x8 av = *(const u16x8*)(rnn + (size_t)(b * NATOMS + idx) * HH + kr);
    u16x8 bv = *(const u16x8*)(W + (size_t)(n0 + lrow) * KFC + k);
    *(u16x8*)&As[lrow][lcol] = av;
    *(u16x8*)&Bs[lrow][lcol] = bv;
    __syncthreads();
    u16x8 afr[2], bfr[2];
#pragma unroll
    for (int mi = 0; mi < 2; mi++)
      afr[mi] = *(const u16x8*)&As[wm + mi * 16 + (lane & 15)][(lane >> 4) * 8];
#pragma unroll
    for (int ni = 0; ni < 2; ni++)
      bfr[ni] = *(const u16x8*)&Bs[wn + ni * 16 + (lane & 15)][(lane >> 4) * 8];
#pragma unroll
    for (int mi = 0; mi < 2; mi++)
#pragma unroll
      for (int ni = 0; ni < 2; ni++) acc[mi][ni] = mfma_bf16(afr[mi], bfr[ni], acc[mi][ni]);
    __syncthreads();
  }
#pragma unroll
  for (int mi = 0; mi < 2; mi++)
#pragma unroll
    for (int ni = 0; ni < 2; ni++) {
      int n = n0 + wn + ni * 16 + (lane & 15);
      float bv = bias[n];
#pragma unroll
      for (int r = 0; r < 4; r++) {
        int mm = m0 + wm + mi * 16 + (lane >> 4) * 4 + r;
        float vv = acc[mi][ni][r] + bv;
        out[(size_t)mm * OUTF + n] = vv >= 0.f ? vv : 0.1f * vv;
      }
    }
}

extern "C" void kernel_launch(void* const* d_in, const int* in_sizes, int n_in,
                              void* d_out, int out_size, void* d_ws, size_t ws_size,
                              hipStream_t stream) {
  const float* x      = (const float*)d_in[0];
  const int*   bonded = (const int*)d_in[1];
  const float* Wih    = (const float*)d_in[2];
  const float* Whh    = (const float*)d_in[3];
  const float* bih    = (const float*)d_in[4];
  const float* bhh    = (const float*)d_in[5];
  const float* Wfc    = (const float*)d_in[6];
  const float* bfc    = (const float*)d_in[7];
  float* out = (float*)d_out;

  char* ws = (char*)d_ws;
  u16* xp   = (u16*)(ws);                                    // 50,331,648 B
  u16* rnn  = (u16*)(ws + 50331648);                         // 16,777,216 B
  u16* whhb = (u16*)(ws + 50331648 + 16777216);              //    393,216 B
  u16* wfcb = (u16*)(ws + 50331648 + 16777216 + 393216);     //    786,432 B

  k_prep<<<(OUTF * KFC + 255) / 256, 256, 0, stream>>>(Whh, whhb, Wfc, wfcb);
  k_xproj<<<dim3(512, 12), 256, 0, stream>>>(x, Wih, bih, xp);
  k_gru<<<32, 512, 0, stream>>>(whhb, bhh, xp, rnn);
  k_fc<<<dim3(512, 4), 256, 0, stream>>>(rnn, bonded, wfcb, bfc, out);
}